// Round 3
// baseline (450.821 us; speedup 1.0000x reference)
//
#include <hip/hip_runtime.h>

// loss = mean((y1/||y1||_row - y1)^2), y1: [N=4e6, D=16] fp32, yinds unused.
// (w - y)^2 = y^2 * (1/||y|| - 1)^2  -> per-lane local sumsq * (rnorm-1)^2.
// Layout: lane handles one float4; 4 consecutive lanes = one row of 16 floats.
//
// Single fused kernel: grid-stride streaming reduce (unroll x4 for MLP of
// loads), one double partial per block, last-block-done finalize (counter in
// d_ws, zeroed by hipMemsetAsync). R2 showed ~290 us of dur_us is harness
// restore/poison traffic (1 GB d_ws fills @155 us in rocprof); our
// controllable slice is ~50-90 us with a 41 us HBM floor (256 MB read).

#define GRID1 2048   // 8 blocks/CU x 4 waves = 32 waves/CU: single generation

__device__ __forceinline__ float quad_term(float4 v) {
    // returns this lane's contribution: local_sumsq * (1/row_norm - 1)^2
    const float local = v.x * v.x + v.y * v.y + v.z * v.z + v.w * v.w;
    float row = local;
    row += __shfl_xor(row, 1);
    row += __shfl_xor(row, 2);          // row sum-of-squares across the quad
    const float c = 1.0f / sqrtf(row) - 1.0f;
    return local * c * c;
}

__global__ __launch_bounds__(256) void mll_fused_kernel(
    const float* __restrict__ y1, unsigned int* __restrict__ counter,
    double* __restrict__ partials, float* __restrict__ out,
    int total4, double inv_m) {
    const int tid    = blockIdx.x * blockDim.x + threadIdx.x;
    const int stride = gridDim.x * blockDim.x;   // multiple of 4

    const float4* __restrict__ y4 = reinterpret_cast<const float4*>(y1);
    float psum = 0.0f;
    int idx = tid;
    // Unrolled x4: 4 independent loads in flight before the dependent
    // shfl/rsqrt chain. total4 % 4 == 0 and stride % 4 == 0 => all 4 lanes
    // of a quad take identical trip counts (shfl-uniform).
    for (; idx + 3 * stride < total4; idx += 4 * stride) {
        const float4 v0 = y4[idx];
        const float4 v1 = y4[idx + stride];
        const float4 v2 = y4[idx + 2 * stride];
        const float4 v3 = y4[idx + 3 * stride];
        psum += quad_term(v0);
        psum += quad_term(v1);
        psum += quad_term(v2);
        psum += quad_term(v3);
    }
    for (; idx < total4; idx += stride) {
        psum += quad_term(y4[idx]);
    }

    // wave64 butterfly reduction
    #pragma unroll
    for (int off = 32; off > 0; off >>= 1)
        psum += __shfl_xor(psum, off);

    __shared__ float wsum[4];  // 256 threads = 4 waves
    const int lane = threadIdx.x & 63;
    const int wave = threadIdx.x >> 6;
    if (lane == 0) wsum[wave] = psum;
    __syncthreads();

    __shared__ bool amLast;
    if (threadIdx.x == 0) {
        partials[blockIdx.x] = (double)(wsum[0] + wsum[1] + wsum[2] + wsum[3]);
        __threadfence();  // release: partial visible device-wide before ticket
        const unsigned int old = atomicAdd(counter, 1u);
        amLast = (old == (unsigned int)(gridDim.x - 1));
    }
    __syncthreads();

    if (amLast) {
        __threadfence();  // acquire: see all blocks' partials
        double s = 0.0;
        for (int i = threadIdx.x; i < GRID1; i += 256) s += partials[i];
        #pragma unroll
        for (int off = 32; off > 0; off >>= 1)
            s += __shfl_xor(s, off);
        __shared__ double dsum[4];
        if (lane == 0) dsum[wave] = s;
        __syncthreads();
        if (threadIdx.x == 0)
            out[0] = (float)((dsum[0] + dsum[1] + dsum[2] + dsum[3]) * inv_m);
    }
}

extern "C" void kernel_launch(void* const* d_in, const int* in_sizes, int n_in,
                              void* d_out, int out_size, void* d_ws, size_t ws_size,
                              hipStream_t stream) {
    const float* y1 = (const float*)d_in[0];
    const int total  = in_sizes[0];      // N*D = 64,000,000
    const int total4 = total / 4;        // 16,000,000 float4 groups

    // d_ws layout: [0..3] counter (zeroed), [8..] GRID1 double partials
    unsigned int* counter = (unsigned int*)d_ws;
    double* partials = (double*)((char*)d_ws + 8);

    hipMemsetAsync(counter, 0, sizeof(unsigned int), stream);
    mll_fused_kernel<<<GRID1, 256, 0, stream>>>(
        y1, counter, partials, (float*)d_out, total4, 1.0 / (double)total);
}

// Round 4
// 347.332 us; speedup vs baseline: 1.2980x; 1.2980x over previous
//
#include <hip/hip_runtime.h>

// loss = mean((y1/||y1||_row - y1)^2), y1: [N=4e6, D=16] fp32, yinds unused.
// Row identity: sum_j y_j^2 (1/||y|| - 1)^2 = S * (rsqrt(S)-1)^2,  S = rowsumsq.
//
// R3 post-mortem: quad-split + __shfl_xor put two serialized LDS-pipe
// round-trips and a precise div+sqrt expansion in every iteration's dependent
// chain -> 202 us at 8% HBM BW (latency-bound, both pipes idle). Fix: one
// thread owns one full row (16 floats = exactly one 64B cacheline = 4
// contiguous in-lane float4 loads). Zero cross-lane ops, one v_rsq per row.
// Two-pass reduction (no atomics, no fences — R3's fused finalize reverted).

#define GRID1 2048   // x256 thr = 524288 threads; ~7.6 rows/thread

__global__ __launch_bounds__(256) void mll_pass1_kernel(
    const float* __restrict__ y1, double* __restrict__ partials, int nrows) {
    const int tid    = blockIdx.x * blockDim.x + threadIdx.x;
    const int stride = gridDim.x * blockDim.x;

    const float4* __restrict__ y4 = reinterpret_cast<const float4*>(y1);
    float psum = 0.0f;
    for (int r = tid; r < nrows; r += stride) {
        const float4 a = y4[4 * r + 0];   // 4 independent back-to-back loads,
        const float4 b = y4[4 * r + 1];   // one 64B line per lane
        const float4 c = y4[4 * r + 2];
        const float4 d = y4[4 * r + 3];
        float S = a.x * a.x + a.y * a.y + a.z * a.z + a.w * a.w;
        S += b.x * b.x + b.y * b.y + b.z * b.z + b.w * b.w;
        S += c.x * c.x + c.y * c.y + c.z * c.z + c.w * c.w;
        S += d.x * d.x + d.y * d.y + d.z * d.z + d.w * d.w;
        const float t = rsqrtf(S) - 1.0f;  // (1/||y|| - 1)
        psum += S * t * t;                 // row's full contribution
    }

    // wave64 butterfly reduction
    #pragma unroll
    for (int off = 32; off > 0; off >>= 1)
        psum += __shfl_xor(psum, off);

    __shared__ float wsum[4];  // 256 threads = 4 waves
    const int lane = threadIdx.x & 63;
    const int wave = threadIdx.x >> 6;
    if (lane == 0) wsum[wave] = psum;
    __syncthreads();
    if (threadIdx.x == 0)
        partials[blockIdx.x] = (double)(wsum[0] + wsum[1] + wsum[2] + wsum[3]);
}

__global__ __launch_bounds__(256) void mll_pass2_kernel(
    const double* __restrict__ partials, float* __restrict__ out,
    int n_partials, double inv_m) {
    double s = 0.0;
    for (int i = threadIdx.x; i < n_partials; i += 256) s += partials[i];
    #pragma unroll
    for (int off = 32; off > 0; off >>= 1)
        s += __shfl_xor(s, off);
    __shared__ double wsum[4];
    const int lane = threadIdx.x & 63;
    const int wave = threadIdx.x >> 6;
    if (lane == 0) wsum[wave] = s;
    __syncthreads();
    if (threadIdx.x == 0)
        out[0] = (float)((wsum[0] + wsum[1] + wsum[2] + wsum[3]) * inv_m);
}

extern "C" void kernel_launch(void* const* d_in, const int* in_sizes, int n_in,
                              void* d_out, int out_size, void* d_ws, size_t ws_size,
                              hipStream_t stream) {
    const float* y1 = (const float*)d_in[0];
    const int total = in_sizes[0];       // N*D = 64,000,000
    const int nrows = total / 16;        // 4,000,000 rows
    double* partials = (double*)d_ws;    // GRID1 doubles, fully overwritten

    mll_pass1_kernel<<<GRID1, 256, 0, stream>>>(y1, partials, nrows);
    mll_pass2_kernel<<<1, 256, 0, stream>>>(partials, (float*)d_out,
                                            GRID1, 1.0 / (double)total);
}

// Round 5
// 342.872 us; speedup vs baseline: 1.3148x; 1.0130x over previous
//
#include <hip/hip_runtime.h>

// loss = mean((y1/||y1||_row - y1)^2), y1: [N=4e6, D=16] fp32, yinds unused.
// Per-lane: local = sum of this lane's float4 squares; row S via quad
// reduction; contribution = local * (rsqrt(S)-1)^2.
//
// R4 post-mortem: R2 (quad-shfl, MLP=1) == R4 (row-per-thread, MLP=4) == ~95us
// @ ~2.8 TB/s -> not wave-latency-bound. Remaining suspects: per-instruction
// coalescing cost (R4's loads touch 64 lines each) / LDS-pipe waits (R2) /
// a ~2.8 TB/s pure-read wall. This version eliminates the first two:
//  - lane i loads consecutive float4s: every instruction = 1KB contiguous,
//    8x128B lines (minimum TA/L1 work)
//  - quad row-reduce via DPP quad_perm (VALU pipe, no LDS round-trip)
//  - 1-deep prefetch keeps a load in flight across each iter's compute
// If this still lands ~95us, the read wall is structural -> roofline.

#define GRID1 2048   // x256 = 524288 threads = 32 waves/CU exactly

__device__ __forceinline__ float dpp_add_xor1(float x) {
    // x + (x from lane^1): quad_perm [1,0,3,2] = 0xB1
    int j = __builtin_amdgcn_mov_dpp(__float_as_int(x), 0xB1, 0xF, 0xF, true);
    return x + __int_as_float(j);
}
__device__ __forceinline__ float dpp_add_xor2(float x) {
    // x + (x from lane^2): quad_perm [2,3,0,1] = 0x4E
    int j = __builtin_amdgcn_mov_dpp(__float_as_int(x), 0x4E, 0xF, 0xF, true);
    return x + __int_as_float(j);
}

__device__ __forceinline__ float row_term(float4 v) {
    const float local = v.x * v.x + v.y * v.y + v.z * v.z + v.w * v.w;
    const float S = dpp_add_xor2(dpp_add_xor1(local));  // row sum-of-squares
    const float t = rsqrtf(S) - 1.0f;                   // (1/||y|| - 1)
    return local * (t * t);
}

__global__ __launch_bounds__(256) void mll_pass1_kernel(
    const float* __restrict__ y1, double* __restrict__ partials, int total4) {
    const int tid    = blockIdx.x * blockDim.x + threadIdx.x;
    const int stride = GRID1 * 256;  // divisible by 4: quads cross bounds together

    const float4* __restrict__ y4 = reinterpret_cast<const float4*>(y1);
    float psum = 0.0f;
    int idx = tid;
    if (idx < total4) {
        float4 cur = y4[idx];
        idx += stride;
        for (; idx < total4; idx += stride) {
            const float4 nxt = y4[idx];   // issued before cur's vmcnt wait
            psum += row_term(cur);
            cur = nxt;
        }
        psum += row_term(cur);
    }

    // wave64 butterfly reduction (once per kernel; shfl cost irrelevant here)
    #pragma unroll
    for (int off = 32; off > 0; off >>= 1)
        psum += __shfl_xor(psum, off);

    __shared__ float wsum[4];  // 256 threads = 4 waves
    const int lane = threadIdx.x & 63;
    const int wave = threadIdx.x >> 6;
    if (lane == 0) wsum[wave] = psum;
    __syncthreads();
    if (threadIdx.x == 0)
        partials[blockIdx.x] = (double)(wsum[0] + wsum[1] + wsum[2] + wsum[3]);
}

__global__ __launch_bounds__(256) void mll_pass2_kernel(
    const double* __restrict__ partials, float* __restrict__ out,
    int n_partials, double inv_m) {
    double s = 0.0;
    for (int i = threadIdx.x; i < n_partials; i += 256) s += partials[i];
    #pragma unroll
    for (int off = 32; off > 0; off >>= 1)
        s += __shfl_xor(s, off);
    __shared__ double wsum[4];
    const int lane = threadIdx.x & 63;
    const int wave = threadIdx.x >> 6;
    if (lane == 0) wsum[wave] = s;
    __syncthreads();
    if (threadIdx.x == 0)
        out[0] = (float)((wsum[0] + wsum[1] + wsum[2] + wsum[3]) * inv_m);
}

extern "C" void kernel_launch(void* const* d_in, const int* in_sizes, int n_in,
                              void* d_out, int out_size, void* d_ws, size_t ws_size,
                              hipStream_t stream) {
    const float* y1 = (const float*)d_in[0];
    const int total  = in_sizes[0];      // N*D = 64,000,000
    const int total4 = total / 4;        // 16,000,000 float4 groups
    double* partials = (double*)d_ws;    // GRID1 doubles, fully overwritten

    mll_pass1_kernel<<<GRID1, 256, 0, stream>>>(y1, partials, total4);
    mll_pass2_kernel<<<1, 256, 0, stream>>>(partials, (float*)d_out,
                                            GRID1, 1.0 / (double)total);
}